// Round 18
// baseline (161.885 us; speedup 1.0000x reference)
//
#include <hip/hip_runtime.h>
#include <hip/hip_bf16.h>

#define B_ 16
#define N_ 256
#define D_ 512
#define H_ 8
#define DK_ 64

typedef unsigned short u16;
typedef __attribute__((ext_vector_type(8))) short bf16x8;
typedef __attribute__((ext_vector_type(4))) float f32x4;

__device__ __forceinline__ float bf2f(u16 u) {
    union { unsigned int i; float f; } v;
    v.i = ((unsigned int)u) << 16;
    return v.f;
}
__device__ __forceinline__ u16 f2bf(float f) {
    union { float f; unsigned int i; } v;
    v.f = f;
    unsigned int x = v.i;
    unsigned int r = (x >> 16) & 1u;
    x += 0x7fffu + r;           // round-to-nearest-even
    return (u16)(x >> 16);
}

// ---------------------------------------------------------------------------
// k_prep: blocks 0..4095 geo (MFMA) | 4096..5119 wtrans | 5120..8191 cvt.
// geo: thread j computes 64 trig features once -> bf16 LDS [256][72];
// waves MFMA features x Wg (8 heads in one n-operand); epilogue via LDS
// bounce for coalesced Sg stores.
// ---------------------------------------------------------------------------
__global__ __launch_bounds__(256) void k_prep(const float* __restrict__ box,
                                              const float* __restrict__ Wg,
                                              const float* __restrict__ bg,
                                              u16* __restrict__ Sg,
                                              const float* __restrict__ W0,
                                              const float* __restrict__ W1,
                                              const float* __restrict__ W2,
                                              const float* __restrict__ W3,
                                              u16* __restrict__ Wt,
                                              const float* __restrict__ X0,
                                              const float* __restrict__ X1,
                                              const float* __restrict__ X2,
                                              u16* __restrict__ Xb) {
    __shared__ __align__(16) unsigned char sh[36864];
    const int tid = threadIdx.x;
    const int bid = blockIdx.x;
    if (bid < 4096) {
        // ---------------- geo part (MFMA) ----------------
        u16* feat = (u16*)sh;                 // [256][72] bf16 features
        const int bi = bid, b = bi >> 8, i = bi & 255;
        const int wid = tid >> 6, lane = tid & 63;
        const int lr = lane & 15, lk8 = (lane >> 4) * 8, quad4 = (lane >> 4) * 4;

        float4 bxi = *(const float4*)&box[(size_t)bi * 4];
        float4 bxj = *(const float4*)&box[(size_t)(b * N_ + tid) * 4];
        float cxi = (bxi.x + bxi.z) * 0.5f, cyi = (bxi.y + bxi.w) * 0.5f;
        float wi = bxi.z - bxi.x + 1.0f, hi = bxi.w - bxi.y + 1.0f;
        float cxj = (bxj.x + bxj.z) * 0.5f, cyj = (bxj.y + bxj.w) * 0.5f;
        float wj = bxj.z - bxj.x + 1.0f, hj = bxj.w - bxj.y + 1.0f;
        float pos[4];
        pos[0] = __logf(fmaxf(fabsf((cxi - cxj) / wi), 1e-3f));
        pos[1] = __logf(fmaxf(fabsf((cyi - cyj) / hi), 1e-3f));
        pos[2] = __logf(wi / wj);
        pos[3] = __logf(hi / hj);
        const float dm[8] = {1.0f, 0.42169650342858224f, 0.1778279410038923f,
                             0.07498942093324559f, 0.03162277660168379f,
                             0.013335214321633241f, 0.005623413251903491f,
                             0.0023713737056616554f};
        const float inv2pi = 0.15915494309189535f;
#pragma unroll
        for (int t = 0; t < 4; ++t) {
            float base = 100.0f * pos[t];
            float sn[8], cs[8];
#pragma unroll
            for (int f = 0; f < 8; ++f) {
                float rev = base * dm[f] * inv2pi;
                rev = rev - floorf(rev);
                sn[f] = __builtin_amdgcn_sinf(rev);
                cs[f] = __builtin_amdgcn_cosf(rev);
            }
            ushort4 p;
            p.x = f2bf(sn[0]); p.y = f2bf(sn[1]); p.z = f2bf(sn[2]); p.w = f2bf(sn[3]);
            *(ushort4*)&feat[tid * 72 + t * 8] = p;
            p.x = f2bf(sn[4]); p.y = f2bf(sn[5]); p.z = f2bf(sn[6]); p.w = f2bf(sn[7]);
            *(ushort4*)&feat[tid * 72 + t * 8 + 4] = p;
            p.x = f2bf(cs[0]); p.y = f2bf(cs[1]); p.z = f2bf(cs[2]); p.w = f2bf(cs[3]);
            *(ushort4*)&feat[tid * 72 + 32 + t * 8] = p;
            p.x = f2bf(cs[4]); p.y = f2bf(cs[5]); p.z = f2bf(cs[6]); p.w = f2bf(cs[7]);
            *(ushort4*)&feat[tid * 72 + 32 + t * 8 + 4] = p;
        }
        // weight fragments (n = head, k = feature); heads 8..15 are zero
        bf16x8 bw0, bw1;
        float bgv = 0.f;
        if (lr < 8) {
            const float* wrow = &Wg[lr * 64];
            float4 a0 = *(const float4*)&wrow[lk8];
            float4 a1 = *(const float4*)&wrow[lk8 + 4];
            float4 a2 = *(const float4*)&wrow[32 + lk8];
            float4 a3 = *(const float4*)&wrow[32 + lk8 + 4];
            bw0[0] = (short)f2bf(a0.x); bw0[1] = (short)f2bf(a0.y);
            bw0[2] = (short)f2bf(a0.z); bw0[3] = (short)f2bf(a0.w);
            bw0[4] = (short)f2bf(a1.x); bw0[5] = (short)f2bf(a1.y);
            bw0[6] = (short)f2bf(a1.z); bw0[7] = (short)f2bf(a1.w);
            bw1[0] = (short)f2bf(a2.x); bw1[1] = (short)f2bf(a2.y);
            bw1[2] = (short)f2bf(a2.z); bw1[3] = (short)f2bf(a2.w);
            bw1[4] = (short)f2bf(a3.x); bw1[5] = (short)f2bf(a3.y);
            bw1[6] = (short)f2bf(a3.z); bw1[7] = (short)f2bf(a3.w);
            bgv = bg[lr];
        } else {
#pragma unroll
            for (int e = 0; e < 8; ++e) { bw0[e] = 0; bw1[e] = 0; }
        }
        __syncthreads();
        // MFMA: wave wid handles j-tiles wid*4 .. wid*4+3
        f32x4 dacc[4];
#pragma unroll
        for (int q = 0; q < 4; ++q) {
            int jt = wid * 4 + q;
            bf16x8 a0 = *(const bf16x8*)&feat[(jt * 16 + lr) * 72 + lk8];
            bf16x8 a1 = *(const bf16x8*)&feat[(jt * 16 + lr) * 72 + 32 + lk8];
            f32x4 z = (f32x4){0.f, 0.f, 0.f, 0.f};
            z = __builtin_amdgcn_mfma_f32_16x16x32_bf16(a0, bw0, z, 0, 0, 0);
            z = __builtin_amdgcn_mfma_f32_16x16x32_bf16(a1, bw1, z, 0, 0, 0);
            dacc[q] = z;
        }
        __syncthreads();   // feat dead; alias as bounce
        u16* bounce = (u16*)sh;   // [8][264]
        if (lr < 8) {
#pragma unroll
            for (int q = 0; q < 4; ++q) {
                int jt = wid * 4 + q;
#pragma unroll
                for (int reg = 0; reg < 4; ++reg) {
                    float wg = dacc[q][reg] + bgv;
                    bounce[lr * 264 + jt * 16 + quad4 + reg] =
                        f2bf(__logf(fmaxf(wg, 1e-6f)));
                }
            }
        }
        __syncthreads();
        {
            int h = tid >> 5, jb = (tid & 31) * 8;
            ushort4 v0 = *(const ushort4*)&bounce[h * 264 + jb];
            ushort4 v1 = *(const ushort4*)&bounce[h * 264 + jb + 4];
            u16* dstp = &Sg[(((size_t)(b * H_ + h) * N_) + i) * N_ + jb];
            *(ushort4*)&dstp[0] = v0;
            *(ushort4*)&dstp[4] = v1;
        }
    } else if (bid < 5120) {
        float (*tt)[33] = (float(*)[33])sh;
        int t = bid - 4096;
        int z = t >> 8, yb = (t >> 4) & 15, xb = t & 15;
        const float* W = (z == 0) ? W0 : (z == 1) ? W1 : (z == 2) ? W2 : W3;
        u16* dst = Wt + (size_t)z * 262144;
        const int kb = yb * 32, nb = xb * 32;
#pragma unroll
        for (int r = 0; r < 4; ++r) {
            int p = r * 256 + tid;
            tt[p >> 5][p & 31] = W[(size_t)(kb + (p >> 5)) * 512 + nb + (p & 31)];
        }
        __syncthreads();
#pragma unroll
        for (int r = 0; r < 4; ++r) {
            int p = r * 256 + tid;
            dst[(size_t)(nb + (p >> 5)) * 512 + kb + (p & 31)] = f2bf(tt[p & 31][p >> 5]);
        }
    } else {
        int t = bid - 5120;
        int z = t >> 10, x = t & 1023;
        const float* X = (z == 0) ? X0 : (z == 1) ? X1 : X2;
        u16* dst = Xb + (size_t)z * 2097152;
        int base = (x * 256 + tid) * 8;
        float4 a = *(const float4*)&X[base];
        float4 b = *(const float4*)&X[base + 4];
        ushort4 oa, ob;
        oa.x = f2bf(a.x); oa.y = f2bf(a.y); oa.z = f2bf(a.z); oa.w = f2bf(a.w);
        ob.x = f2bf(b.x); ob.y = f2bf(b.y); ob.z = f2bf(b.z); ob.w = f2bf(b.w);
        *(ushort4*)&dst[base] = oa;
        *(ushort4*)&dst[base + 4] = ob;
    }
}

// ---------------------------------------------------------------------------
// k_gemm_qkv: r17 verbatim (XCD swizzle: grid (64,8,3), id%8 = m%8).
// ---------------------------------------------------------------------------
__global__ __launch_bounds__(256) void k_gemm_qkv(const u16* __restrict__ Xb,
                                                  const u16* __restrict__ Wtb,
                                                  const float* __restrict__ bq,
                                                  const float* __restrict__ bk,
                                                  const float* __restrict__ bv,
                                                  u16* __restrict__ qkv) {
    const int z = blockIdx.z;
    const u16* Ab = Xb + (size_t)z * 2097152;
    const u16* Wt = Wtb + (size_t)z * 262144;
    const float* bias = (z == 0) ? bq : (z == 1) ? bk : bv;
    u16* dst = qkv + (size_t)z * 2097152;

    __shared__ u16 As[2][64][72];
    __shared__ u16 Bs[2][64][72];
    const int tid = threadIdx.x;
    const int m0 = blockIdx.x * 64, n0 = blockIdx.y * 64;
    const int wid = tid >> 6, lane = tid & 63;
    const int wm = (wid & 1) * 32, wn = (wid >> 1) * 32;
    const int lr = lane & 15, lk8 = (lane >> 4) * 8, quad4 = (lane >> 4) * 4;

    f32x4 acc[2][2];
#pragma unroll
    for (int mi = 0; mi < 2; ++mi)
#pragma unroll
        for (int ni = 0; ni < 2; ++ni) acc[mi][ni] = (f32x4){0.f, 0.f, 0.f, 0.f};

    ushort4 ra[4], rb[4];
#pragma unroll
    for (int r = 0; r < 4; ++r) {
        int p = r * 256 + tid, row = p >> 4, c4 = (p & 15) * 4;
        ra[r] = *(const ushort4*)&Ab[(size_t)(m0 + row) * 512 + c4];
        rb[r] = *(const ushort4*)&Wt[(size_t)(n0 + row) * 512 + c4];
    }
#pragma unroll
    for (int r = 0; r < 4; ++r) {
        int p = r * 256 + tid, row = p >> 4, c4 = (p & 15) * 4;
        *(ushort4*)&As[0][row][c4] = ra[r];
        *(ushort4*)&Bs[0][row][c4] = rb[r];
    }
    __syncthreads();
    for (int it = 0; it < 8; ++it) {
        const int cur = it & 1;
        if (it < 7) {
            int k0n = (it + 1) * 64;
#pragma unroll
            for (int r = 0; r < 4; ++r) {
                int p = r * 256 + tid, row = p >> 4, c4 = (p & 15) * 4;
                ra[r] = *(const ushort4*)&Ab[(size_t)(m0 + row) * 512 + k0n + c4];
                rb[r] = *(const ushort4*)&Wt[(size_t)(n0 + row) * 512 + k0n + c4];
            }
        }
#pragma unroll
        for (int ks = 0; ks < 64; ks += 32) {
            bf16x8 af[2], bfx[2];
#pragma unroll
            for (int mi = 0; mi < 2; ++mi)
                af[mi] = *(const bf16x8*)&As[cur][wm + mi * 16 + lr][ks + lk8];
#pragma unroll
            for (int ni = 0; ni < 2; ++ni)
                bfx[ni] = *(const bf16x8*)&Bs[cur][wn + ni * 16 + lr][ks + lk8];
#pragma unroll
            for (int mi = 0; mi < 2; ++mi)
#pragma unroll
                for (int ni = 0; ni < 2; ++ni)
                    acc[mi][ni] = __builtin_amdgcn_mfma_f32_16x16x32_bf16(
                        af[mi], bfx[ni], acc[mi][ni], 0, 0, 0);
        }
        if (it < 7) {
#pragma unroll
            for (int r = 0; r < 4; ++r) {
                int p = r * 256 + tid, row = p >> 4, c4 = (p & 15) * 4;
                *(ushort4*)&As[1 - cur][row][c4] = ra[r];
                *(ushort4*)&Bs[1 - cur][row][c4] = rb[r];
            }
            __syncthreads();
        }
    }
    u16* bounce = &As[0][0][0];
    const float scale = (z == 0) ? 0.125f : 1.0f;
    const int h = n0 >> 6, b = m0 >> 8, rrb = m0 & 255;
    if (z == 2) {
#pragma unroll
        for (int mi = 0; mi < 2; ++mi)
#pragma unroll
            for (int ni = 0; ni < 2; ++ni) {
                int cn = wn + ni * 16 + lr;
                float bb = bias[n0 + cn];
#pragma unroll
                for (int reg = 0; reg < 4; ++reg) {
                    int rm = wm + mi * 16 + quad4 + reg;
                    bounce[cn * 72 + rm] = f2bf(acc[mi][ni][reg] + bb);
                }
            }
        __syncthreads();
#pragma unroll
        for (int r = 0; r < 4; ++r) {
            int p = r * 256 + tid, dn = p >> 4, c4 = (p & 15) * 4;
            *(ushort4*)&dst[(((size_t)(b * H_ + h) * DK_) + dn) * N_ + rrb + c4] =
                *(const ushort4*)&bounce[dn * 72 + c4];
        }
    } else {
#pragma unroll
        for (int mi = 0; mi < 2; ++mi)
#pragma unroll
            for (int ni = 0; ni < 2; ++ni) {
                int cn = wn + ni * 16 + lr;
                float bb = bias[n0 + cn];
#pragma unroll
                for (int reg = 0; reg < 4; ++reg) {
                    int rm = wm + mi * 16 + quad4 + reg;
                    bounce[rm * 72 + cn] = f2bf((acc[mi][ni][reg] + bb) * scale);
                }
            }
        __syncthreads();
#pragma unroll
        for (int r = 0; r < 4; ++r) {
            int p = r * 256 + tid, rm = p >> 4, c4 = (p & 15) * 4;
            *(ushort4*)&dst[(((size_t)(b * H_ + h) * N_) + rrb + rm) * DK_ + c4] =
                *(const ushort4*)&bounce[rm * 72 + c4];
        }
    }
}

// ---------------------------------------------------------------------------
// k_gemm_out: r17 verbatim (XCD swizzle grid (64,8)).
// ---------------------------------------------------------------------------
__global__ __launch_bounds__(256) void k_gemm_out(const u16* __restrict__ Ab,
                                                  const u16* __restrict__ Wt,
                                                  const float* __restrict__ bias,
                                                  float* __restrict__ outp) {
    __shared__ u16 As[2][64][72];
    __shared__ u16 Bs[2][64][72];
    const int tid = threadIdx.x;
    const int m0 = blockIdx.x * 64, n0 = blockIdx.y * 64;
    const int wid = tid >> 6, lane = tid & 63;
    const int wm = (wid & 1) * 32, wn = (wid >> 1) * 32;
    const int lr = lane & 15, lk8 = (lane >> 4) * 8;
    f32x4 acc[2][2];
#pragma unroll
    for (int mi = 0; mi < 2; ++mi)
#pragma unroll
        for (int ni = 0; ni < 2; ++ni) acc[mi][ni] = (f32x4){0.f, 0.f, 0.f, 0.f};
    ushort4 ra[4], rb[4];
#pragma unroll
    for (int r = 0; r < 4; ++r) {
        int p = r * 256 + tid, row = p >> 4, c4 = (p & 15) * 4;
        ra[r] = *(const ushort4*)&Ab[(size_t)(m0 + row) * 512 + c4];
        rb[r] = *(const ushort4*)&Wt[(size_t)(n0 + row) * 512 + c4];
    }
#pragma unroll
    for (int r = 0; r < 4; ++r) {
        int p = r * 256 + tid, row = p >> 4, c4 = (p & 15) * 4;
        *(ushort4*)&As[0][row][c4] = ra[r];
        *(ushort4*)&Bs[0][row][c4] = rb[r];
    }
    __syncthreads();
    for (int it = 0; it < 8; ++it) {
        const int cur = it & 1;
        if (it < 7) {
            int k0n = (it + 1) * 64;
#pragma unroll
            for (int r = 0; r < 4; ++r) {
                int p = r * 256 + tid, row = p >> 4, c4 = (p & 15) * 4;
                ra[r] = *(const ushort4*)&Ab[(size_t)(m0 + row) * 512 + k0n + c4];
                rb[r] = *(const ushort4*)&Wt[(size_t)(n0 + row) * 512 + k0n + c4];
            }
        }
#pragma unroll
        for (int ks = 0; ks < 64; ks += 32) {
            bf16x8 af[2], bfx[2];
#pragma unroll
            for (int mi = 0; mi < 2; ++mi)
                af[mi] = *(const bf16x8*)&As[cur][wm + mi * 16 + lr][ks + lk8];
#pragma unroll
            for (int ni = 0; ni < 2; ++ni)
                bfx[ni] = *(const bf16x8*)&Bs[cur][wn + ni * 16 + lr][ks + lk8];
#pragma unroll
            for (int mi = 0; mi < 2; ++mi)
#pragma unroll
                for (int ni = 0; ni < 2; ++ni)
                    acc[mi][ni] = __builtin_amdgcn_mfma_f32_16x16x32_bf16(
                        af[mi], bfx[ni], acc[mi][ni], 0, 0, 0);
        }
        if (it < 7) {
#pragma unroll
            for (int r = 0; r < 4; ++r) {
                int p = r * 256 + tid, row = p >> 4, c4 = (p & 15) * 4;
                *(ushort4*)&As[1 - cur][row][c4] = ra[r];
                *(ushort4*)&Bs[1 - cur][row][c4] = rb[r];
            }
            __syncthreads();
        }
    }
#pragma unroll
    for (int mi = 0; mi < 2; ++mi)
#pragma unroll
        for (int ni = 0; ni < 2; ++ni) {
            int col = n0 + wn + ni * 16 + lr;
            float bb = bias[col];
#pragma unroll
            for (int reg = 0; reg < 4; ++reg) {
                int m = m0 + wm + mi * 16 + (lane >> 4) * 4 + reg;
                outp[(size_t)m * 512 + col] = acc[mi][ni][reg] + bb;
            }
        }
}

// ---------------------------------------------------------------------------
// k_attn v4 (r17 verbatim): 64-row i-tile, grid (128 bh, 4).
// ---------------------------------------------------------------------------
__global__ __launch_bounds__(256) void k_attn(const u16* __restrict__ qh,
                                              const u16* __restrict__ kh,
                                              const u16* __restrict__ vhT,
                                              const u16* __restrict__ Sg,
                                              u16* __restrict__ attnb) {
    __shared__ __align__(16) unsigned char smem[63488];
    u16* sQ = (u16*)smem;                     // [64][72]
    u16* sP = (u16*)(smem + 9216);            // [64][264]
    u16* sK = (u16*)(smem + 43008);           // [128][72], aliased:
    u16* sVt = (u16*)(smem + 43008);          // [64][136]
    float* sRedM = (float*)(smem + 61440);    // [64][4]
    float* sRedS = (float*)(smem + 62464);    // [64][4]

    const int tid = threadIdx.x;
    const int bh = blockIdx.x;
    const int i0 = blockIdx.y * 64;
    const int b = bh >> 3, h = bh & 7;
    const int wid = tid >> 6, lane = tid & 63;
    const int lr = lane & 15, lk8 = (lane >> 4) * 8, quad4 = (lane >> 4) * 4;

#pragma unroll
    for (int r = 0; r < 4; ++r) {
        int p = r * 256 + tid, i = p >> 4, d0 = (p & 15) * 4;
        *(ushort4*)&sQ[i * 72 + d0] =
            *(const ushort4*)&qh[((size_t)bh * N_ + i0 + i) * DK_ + d0];
    }
#pragma unroll
    for (int r = 0; r < 16; ++r) {
        int p = r * 256 + tid, row = p >> 6, jc = (p & 63) * 4;
        *(ushort4*)&sP[row * 264 + jc] =
            *(const ushort4*)&Sg[(((size_t)bh * N_) + i0 + row) * N_ + jc];
    }
#pragma unroll
    for (int r = 0; r < 8; ++r) {
        int p = r * 256 + tid, j = p >> 4, d0 = (p & 15) * 4;
        *(ushort4*)&sK[j * 72 + d0] =
            *(const ushort4*)&kh[((size_t)bh * N_ + j) * DK_ + d0];
    }
    __syncthreads();

    ushort4 kpre[8];
#pragma unroll
    for (int r = 0; r < 8; ++r) {
        int p = r * 256 + tid, j = p >> 4, d0 = (p & 15) * 4;
        kpre[r] = *(const ushort4*)&kh[((size_t)bh * N_ + 128 + j) * DK_ + d0];
    }
    f32x4 acc[2][4][2];
#pragma unroll
    for (int c = 0; c < 2; ++c)
#pragma unroll
        for (int mi = 0; mi < 4; ++mi)
#pragma unroll
            for (int ni = 0; ni < 2; ++ni) acc[c][mi][ni] = (f32x4){0.f, 0.f, 0.f, 0.f};
#pragma unroll
    for (int ks = 0; ks < 64; ks += 32) {
        bf16x8 af[4], bfx[2];
#pragma unroll
        for (int mi = 0; mi < 4; ++mi)
            af[mi] = *(const bf16x8*)&sQ[(mi * 16 + lr) * 72 + ks + lk8];
#pragma unroll
        for (int ni = 0; ni < 2; ++ni)
            bfx[ni] = *(const bf16x8*)&sK[(wid * 32 + ni * 16 + lr) * 72 + ks + lk8];
#pragma unroll
        for (int mi = 0; mi < 4; ++mi)
#pragma unroll
            for (int ni = 0; ni < 2; ++ni)
                acc[0][mi][ni] = __builtin_amdgcn_mfma_f32_16x16x32_bf16(
                    af[mi], bfx[ni], acc[0][mi][ni], 0, 0, 0);
    }
    __syncthreads();
#pragma unroll
    for (int r = 0; r < 8; ++r) {
        int p = r * 256 + tid, j = p >> 4, d0 = (p & 15) * 4;
        *(ushort4*)&sK[j * 72 + d0] = kpre[r];
    }
    __syncthreads();
#pragma unroll
    for (int ks = 0; ks < 64; ks += 32) {
        bf16x8 af[4], bfx[2];
#pragma unroll
        for (int mi = 0; mi < 4; ++mi)
            af[mi] = *(const bf16x8*)&sQ[(mi * 16 + lr) * 72 + ks + lk8];
#pragma unroll
        for (int ni = 0; ni < 2; ++ni)
            bfx[ni] = *(const bf16x8*)&sK[(wid * 32 + ni * 16 + lr) * 72 + ks + lk8];
#pragma unroll
        for (int mi = 0; mi < 4; ++mi)
#pragma unroll
            for (int ni = 0; ni < 2; ++ni)
                acc[1][mi][ni] = __builtin_amdgcn_mfma_f32_16x16x32_bf16(
                    af[mi], bfx[ni], acc[1][mi][ni], 0, 0, 0);
    }
    __syncthreads();

#pragma unroll
    for (int r = 0; r < 8; ++r) {
        int p = r * 256 + tid, d = p >> 5, jc = (p & 31) * 4;
        *(ushort4*)&sVt[d * 136 + jc] =
            *(const ushort4*)&vhT[(((size_t)bh * DK_) + d) * N_ + jc];
    }
#pragma unroll
    for (int c = 0; c < 2; ++c)
#pragma unroll
        for (int mi = 0; mi < 4; ++mi)
#pragma unroll
            for (int ni = 0; ni < 2; ++ni) {
                int col = c * 128 + wid * 32 + ni * 16 + lr;
#pragma unroll
                for (int reg = 0; reg < 4; ++reg) {
                    int row = mi * 16 + quad4 + reg;
                    acc[c][mi][ni][reg] += bf2f(sP[row * 264 + col]);
                }
            }
    float mrow[4][4];
#pragma unroll
    for (int mi = 0; mi < 4; ++mi)
#pragma unroll
        for (int reg = 0; reg < 4; ++reg) {
            float m = acc[0][mi][0][reg];
            m = fmaxf(m, acc[0][mi][1][reg]);
            m = fmaxf(m, acc[1][mi][0][reg]);
            m = fmaxf(m, acc[1][mi][1][reg]);
#pragma unroll
            for (int off = 1; off <= 8; off <<= 1) m = fmaxf(m, __shfl_xor(m, off, 64));
            mrow[mi][reg] = m;
        }
    if (lr == 0) {
#pragma unroll
        for (int mi = 0; mi < 4; ++mi)
#pragma unroll
            for (int reg = 0; reg < 4; ++reg)
                sRedM[(mi * 16 + quad4 + reg) * 4 + wid] = mrow[mi][reg];
    }
    __syncthreads();
    float gm[4][4], sl[4][4];
#pragma unroll
    for (int mi = 0; mi < 4; ++mi)
#pragma unroll
        for (int reg = 0; reg < 4; ++reg) {
            float4 mm = *(const float4*)&sRedM[(mi * 16 + quad4 + reg) * 4];
            gm[mi][reg] = fmaxf(fmaxf(mm.x, mm.y), fmaxf(mm.z, mm.w));
            sl[mi][reg] = 0.f;
        }
#pragma unroll
    for (int c = 0; c < 2; ++c)
#pragma unroll
        for (int mi = 0; mi < 4; ++mi)
#pragma unroll
            for (int ni = 0; ni < 2; ++ni)
#pragma unroll
                for (int reg = 0; reg < 4; ++reg) {
                    float e = __expf(acc[c][mi][ni][reg] - gm[mi][reg]);
                    acc[c][mi][ni][reg] = e;
                    sl[mi][reg] += e;
                }
#pragma unroll
    for (int mi = 0; mi < 4; ++mi)
#pragma unroll
        for (int reg = 0; reg < 4; ++reg) {
            float s = sl[mi][reg];
#pragma unroll
            for (int off = 1; off <= 8; off <<= 1) s += __shfl_xor(s, off, 64);
            sl[mi][reg] = s;
        }
    if (lr == 0) {
#pragma unroll
        for (int mi = 0; mi < 4; ++mi)
#pragma unroll
            for (int reg = 0; reg < 4; ++reg)
                sRedS[(mi * 16 + quad4 + reg) * 4 + wid] = sl[mi][reg];
    }
    __syncthreads();
#pragma unroll
    for (int mi = 0; mi < 4; ++mi)
#pragma unroll
        for (int reg = 0; reg < 4; ++reg) {
            float4 ss = *(const float4*)&sRedS[(mi * 16 + quad4 + reg) * 4];
            gm[mi][reg] = 1.0f / (ss.x + ss.y + ss.z + ss.w);
        }
#pragma unroll
    for (int c = 0; c < 2; ++c)
#pragma unroll
        for (int mi = 0; mi < 4; ++mi)
#pragma unroll
            for (int ni = 0; ni < 2; ++ni) {
                int col = c * 128 + wid * 32 + ni * 16 + lr;
#pragma unroll
                for (int reg = 0; reg < 4; ++reg) {
                    int row = mi * 16 + quad4 + reg;
                    sP[row * 264 + col] = f2bf(acc[c][mi][ni][reg] * gm[mi][reg]);
                }
            }
    __syncthreads();

    f32x4 o[4];
#pragma unroll
    for (int mi = 0; mi < 4; ++mi) o[mi] = (f32x4){0.f, 0.f, 0.f, 0.f};
#pragma unroll
    for (int k0 = 0; k0 < 128; k0 += 32) {
        bf16x8 bfx = *(const bf16x8*)&sVt[(wid * 16 + lr) * 136 + k0 + lk8];
#pragma unroll
        for (int mi = 0; mi < 4; ++mi) {
            bf16x8 af = *(const bf16x8*)&sP[(mi * 16 + lr) * 264 + k0 + lk8];
            o[mi] = __builtin_amdgcn_mfma_f32_16x16x32_bf16(af, bfx, o[mi], 0, 0, 0);
        }
    }
    __syncthreads();
#pragma unroll
    for (int r = 0; r < 8; ++r) {
        int p = r * 256 + tid, d = p >> 5, jc = (p & 31) * 4;
        *(ushort4*)&sVt[d * 136 + jc] =
            *(const ushort4*)&vhT[(((size_t)bh * DK_) + d) * N_ + 128 + jc];
    }
    __syncthreads();
#pragma unroll
    for (int k0 = 0; k0 < 128; k0 += 32) {
        bf16x8 bfx = *(const bf16x8*)&sVt[(wid * 16 + lr) * 136 + k0 + lk8];
#pragma unroll
        for (int mi = 0; mi < 4; ++mi) {
            bf16x8 af = *(const bf16x8*)&sP[(mi * 16 + lr) * 264 + 128 + k0 + lk8];
            o[mi] = __builtin_amdgcn_mfma_f32_16x16x32_bf16(af, bfx, o[mi], 0, 0, 0);
        }
    }
#pragma unroll
    for (int mi = 0; mi < 4; ++mi)
#pragma unroll
        for (int reg = 0; reg < 4; ++reg) {
            int row = mi * 16 + quad4 + reg;
            attnb[((size_t)(b * N_ + i0 + row)) * D_ + h * 64 + wid * 16 + lr] =
                f2bf(o[mi][reg]);
        }
}

extern "C" void kernel_launch(void* const* d_in, const int* in_sizes, int n_in,
                              void* d_out, int out_size, void* d_ws, size_t ws_size,
                              hipStream_t stream) {
    const float* Xq = (const float*)d_in[0];
    const float* Xk = (const float*)d_in[1];
    const float* Xv = (const float*)d_in[2];
    const float* box = (const float*)d_in[3];
    const float* Wq = (const float*)d_in[4];
    const float* bq = (const float*)d_in[5];
    const float* Wk = (const float*)d_in[6];
    const float* bk = (const float*)d_in[7];
    const float* Wv = (const float*)d_in[8];
    const float* bv = (const float*)d_in[9];
    const float* Wo = (const float*)d_in[10];
    const float* bo = (const float*)d_in[11];
    const float* Wg = (const float*)d_in[12];
    const float* bg = (const float*)d_in[13];
    float* out = (float*)d_out;

    // ws (u16 units): [0,6M) qkv | [6M,14.39M) Sg | [14M,16M) attnb |
    // [16M,17.05M) Wt | [18M,24.3M) Xb.
    u16* ws16 = (u16*)d_ws;
    u16* qkv = ws16;
    u16* qh = qkv;
    u16* kh = qkv + 2097152;
    u16* vhT = qkv + 4194304;
    u16* Sg = ws16 + 6291456;
    u16* attnb = ws16 + 14680064;
    u16* Wt = ws16 + 16777216;
    u16* Xb = ws16 + 18874368;

    dim3 blk(256);
    k_prep<<<dim3(8192), blk, 0, stream>>>(box, Wg, bg, Sg, Wq, Wk, Wv, Wo, Wt,
                                           Xq, Xk, Xv, Xb);
    k_gemm_qkv<<<dim3(64, 8, 3), blk, 0, stream>>>(Xb, Wt, bq, bk, bv, qkv);
    k_attn<<<dim3(128, 4), blk, 0, stream>>>(qh, kh, vhT, Sg, attnb);
    k_gemm_out<<<dim3(64, 8), blk, 0, stream>>>(attnb, Wt + 3 * 262144, bo, out);
}